// Round 1
// baseline (492.230 us; speedup 1.0000x reference)
//
#include <hip/hip_runtime.h>

#define B_N 16384
#define IN_D 512
#define H1_D 512
#define H2_D 256
#define H3_D 128
#define A_D 16
#define E_N 9
#define TILE 32
#define THREADS 512
#define LSTRIDE 516  // floats; 516*4=2064 bytes, 16B-aligned rows

// ws header (ints): [0]=int64 flag, [8..16]=counts[9], [24..32]=cursors[9]
// then idx[B] at int offset 64, expert[B] at 64+B

__global__ void k_init(const int* pos32, int* hdr) {
  int t = threadIdx.x;
  if (t > 0 && t < 64) hdr[t] = 0;
  if (t == 0) {
    // If position is int64 (values 0..8), every high word is 0.
    int nz = 0;
    for (int i = 0; i < 64; ++i) nz |= pos32[2 * i + 1];
    hdr[0] = (nz == 0) ? 1 : 0;
  }
}

__global__ void k_count(const int* pos, int* hdr, int* expert) {
  int i = blockIdx.x * blockDim.x + threadIdx.x;
  if (i >= B_N) return;
  int flag = hdr[0];
  long long v = flag ? ((const long long*)pos)[i] : (long long)pos[i];
  if (v < 0) v = 0;
  if (v > 8) v = 8;
  int e = (int)v;
  expert[i] = e;
  atomicAdd(&hdr[8 + e], 1);
}

__global__ void k_scan(int* hdr) {
  if (threadIdx.x == 0 && blockIdx.x == 0) {
    int acc = 0;
    for (int e = 0; e < E_N; ++e) { hdr[24 + e] = acc; acc += hdr[8 + e]; }
  }
}

__global__ void k_scatter(const int* expert, int* hdr, int* idx) {
  int i = blockIdx.x * blockDim.x + threadIdx.x;
  if (i >= B_N) return;
  int e = expert[i];
  int slot = atomicAdd(&hdr[24 + e], 1);
  idx[slot] = i;
}

template <int INDIM, int OUTDIM>
__device__ __forceinline__ void layer(const float* __restrict__ W,
                                      const float* __restrict__ bias,
                                      const float* __restrict__ in_lds,
                                      float* __restrict__ out_lds, int t) {
  constexpr int OT = OUTDIM / 64;  // outputs per thread (8 s-groups x 64 o-groups)
  const int sg = t & 7;
  const int og = t >> 3;
  float acc[4][OT];
#pragma unroll
  for (int si = 0; si < 4; ++si)
#pragma unroll
    for (int j = 0; j < OT; ++j) acc[si][j] = 0.f;

  for (int k = 0; k < INDIM; k += 4) {
    float4 xv[4];
#pragma unroll
    for (int si = 0; si < 4; ++si)
      xv[si] = *(const float4*)&in_lds[(sg * 4 + si) * LSTRIDE + k];
#pragma unroll
    for (int j = 0; j < OT; ++j) {
      const int o = og * OT + j;
      float4 wv = *(const float4*)&W[o * INDIM + k];
#pragma unroll
      for (int si = 0; si < 4; ++si) {
        acc[si][j] = fmaf(xv[si].x, wv.x, acc[si][j]);
        acc[si][j] = fmaf(xv[si].y, wv.y, acc[si][j]);
        acc[si][j] = fmaf(xv[si].z, wv.z, acc[si][j]);
        acc[si][j] = fmaf(xv[si].w, wv.w, acc[si][j]);
      }
    }
  }
#pragma unroll
  for (int j = 0; j < OT; ++j) {
    const int o = og * OT + j;
    const float bb = bias[o];
#pragma unroll
    for (int si = 0; si < 4; ++si) {
      float v = acc[si][j] + bb;
      out_lds[(sg * 4 + si) * LSTRIDE + o] = v > 0.f ? v : 0.f;
    }
  }
}

__launch_bounds__(THREADS)
__global__ void k_mlp(const float* __restrict__ x,
                      const float* __restrict__ W1, const float* __restrict__ b1,
                      const float* __restrict__ W2, const float* __restrict__ b2,
                      const float* __restrict__ W3, const float* __restrict__ b3,
                      const float* __restrict__ W4, const float* __restrict__ b4,
                      const int* __restrict__ hdr, const int* __restrict__ idx,
                      float* __restrict__ out) {
  __shared__ __align__(16) float bufA[TILE * LSTRIDE];
  __shared__ __align__(16) float bufB[TILE * LSTRIDE];

  const int* counts = hdr + 8;
  int b = blockIdx.x;
  int e = -1, tile = 0, base = 0, ne = 0;
  {
    int acc = 0, off = 0;
    for (int ee = 0; ee < E_N; ++ee) {
      int n = counts[ee];
      int nt = (n + TILE - 1) / TILE;
      if (b < acc + nt) { e = ee; tile = b - acc; ne = n; base = off; break; }
      acc += nt; off += n;
    }
  }
  if (e < 0) return;
  const int r = min(TILE, ne - tile * TILE);  // valid rows in this tile
  const int t = threadIdx.x;
  const int row0 = base + tile * TILE;

  // Stage x rows (gathered) into bufA; zero-fill invalid rows.
  for (int u = t; u < TILE * (IN_D / 4); u += THREADS) {
    int s = u >> 7;           // /128 float4s per row
    int k4 = u & 127;
    float4 v = make_float4(0.f, 0.f, 0.f, 0.f);
    if (s < r) {
      int row = idx[row0 + s];
      v = ((const float4*)x)[row * (IN_D / 4) + k4];
    }
    *(float4*)&bufA[s * LSTRIDE + k4 * 4] = v;
  }
  __syncthreads();

  layer<IN_D, H1_D>(W1 + e * H1_D * IN_D, b1 + e * H1_D, bufA, bufB, t);
  __syncthreads();
  layer<H1_D, H2_D>(W2 + e * H2_D * H1_D, b2 + e * H2_D, bufB, bufA, t);
  __syncthreads();
  layer<H2_D, H3_D>(W3 + e * H3_D * H2_D, b3 + e * H3_D, bufA, bufB, t);
  __syncthreads();

  // Layer 4 + softmax: thread t -> sample s = t>>4, class a = t&15
  {
    const int s = t >> 4;
    const int a = t & 15;
    const float* w4 = W4 + e * A_D * H3_D + a * H3_D;
    float accv = b4[e * A_D + a];
    for (int k = 0; k < H3_D; k += 4) {
      float4 h = *(const float4*)&bufB[s * LSTRIDE + k];
      float4 wv = *(const float4*)&w4[k];
      accv = fmaf(h.x, wv.x, accv);
      accv = fmaf(h.y, wv.y, accv);
      accv = fmaf(h.z, wv.z, accv);
      accv = fmaf(h.w, wv.w, accv);
    }
    float m = accv;
    for (int msk = 8; msk >= 1; msk >>= 1) m = fmaxf(m, __shfl_xor(m, msk));
    float p = expf(accv - m);
    float ssum = p;
    for (int msk = 8; msk >= 1; msk >>= 1) ssum += __shfl_xor(ssum, msk);
    if (s < r) {
      int row = idx[row0 + s];
      out[row * A_D + a] = p / ssum;
    }
  }
}

extern "C" void kernel_launch(void* const* d_in, const int* in_sizes, int n_in,
                              void* d_out, int out_size, void* d_ws, size_t ws_size,
                              hipStream_t stream) {
  const float* x  = (const float*)d_in[0];
  const int* pos  = (const int*)d_in[1];
  const float* W1 = (const float*)d_in[2];
  const float* b1 = (const float*)d_in[3];
  const float* W2 = (const float*)d_in[4];
  const float* b2 = (const float*)d_in[5];
  const float* W3 = (const float*)d_in[6];
  const float* b3 = (const float*)d_in[7];
  const float* W4 = (const float*)d_in[8];
  const float* b4 = (const float*)d_in[9];
  float* out = (float*)d_out;

  int* hdr = (int*)d_ws;
  int* idx = hdr + 64;
  int* expert = idx + B_N;

  hipLaunchKernelGGL(k_init, dim3(1), dim3(64), 0, stream, pos, hdr);
  hipLaunchKernelGGL(k_count, dim3(B_N / 256), dim3(256), 0, stream, pos, hdr, expert);
  hipLaunchKernelGGL(k_scan, dim3(1), dim3(1), 0, stream, hdr);
  hipLaunchKernelGGL(k_scatter, dim3(B_N / 256), dim3(256), 0, stream, expert, hdr, idx);

  const int nblocks = B_N / TILE + E_N - 1;  // upper bound on sum of per-expert tiles
  hipLaunchKernelGGL(k_mlp, dim3(nblocks), dim3(THREADS), 0, stream,
                     x, W1, b1, W2, b2, W3, b3, W4, b4, hdr, idx, out);
}

// Round 2
// 295.849 us; speedup vs baseline: 1.6638x; 1.6638x over previous
//
#include <hip/hip_runtime.h>

typedef __attribute__((ext_vector_type(8))) short bf16x8;
typedef __attribute__((ext_vector_type(4))) float f32x4;

#define MFMA(a, b, c) __builtin_amdgcn_mfma_f32_16x16x32_bf16(a, b, c, 0, 0, 0)

#define B_N 16384
#define E_N 9
#define TILE 32
#define NTILE_MAX (B_N / TILE + E_N - 1)  // 520
#define THREADS 512

// dims
#define D_IN 512
#define D_H1 512
#define D_H2 256
#define D_H3 128
#define D_A 16

// weight plane element offsets (ushort elems within each plane)
#define O_W1 0
#define O_W2 2359296
#define O_W3 3538944
#define O_W4 3833856
#define W_ELEMS 3852288
#define S_W1 2359296
#define S_W2 1179648
#define S_W3 294912
#define S_W4 18432

// ws layout
#define IDX_OFF 64
#define EXP_OFF (64 + B_N)
#define WB_OFF 131584                                  // byte offset of hi plane (16B aligned)
#define WS_NEED (WB_OFF + (size_t)W_ELEMS * 4)         // hi+lo bf16 planes

// LDS layout (bytes). TILE=32.
#define XH_OFF 0        // x hi: [32][512] bf16, stride 1024
#define XL_OFF 32768    // x lo
#define H1P_OFF 65536   // h1 panel bf16-only: [32][128], stride 256
#define LDS_BYTES 73728
#define H2H_OFF 0       // reuse x region: h2 hi [32][256], stride 512
#define H2L_OFF 16384
#define H3H_OFF 32768   // h3 hi [32][128], stride 256
#define H3L_OFF 40960

__device__ __forceinline__ unsigned short f2bf(float f) {
  unsigned u = __float_as_uint(f);
  u += 0x7fffu + ((u >> 16) & 1u);   // round-to-nearest-even
  return (unsigned short)(u >> 16);
}
__device__ __forceinline__ float bf2f(unsigned short h) {
  return __uint_as_float(((unsigned)h) << 16);
}

// ---------------- preprocessing ----------------

__global__ void k_init(const int* pos32, int* hdr) {
  int t = threadIdx.x;
  if (t > 0 && t < 64) hdr[t] = 0;
  if (t == 0) {
    int nz = 0;
    for (int i = 0; i < 64; ++i) nz |= pos32[2 * i + 1];
    hdr[0] = (nz == 0) ? 1 : 0;  // int64 layout flag
  }
}

__global__ void k_count(const int* pos, int* hdr, int* expert) {
  int i = blockIdx.x * blockDim.x + threadIdx.x;
  if (i >= B_N) return;
  int flag = hdr[0];
  long long v = flag ? ((const long long*)pos)[i] : (long long)pos[i];
  if (v < 0) v = 0;
  if (v > 8) v = 8;
  int e = (int)v;
  expert[i] = e;
  atomicAdd(&hdr[8 + e], 1);
}

__global__ void k_scan(int* hdr) {
  if (threadIdx.x == 0 && blockIdx.x == 0) {
    int acc = 0;
    for (int e = 0; e < E_N; ++e) { hdr[24 + e] = acc; acc += hdr[8 + e]; }
  }
}

__global__ void k_scatter(const int* expert, int* hdr, int* idx) {
  int i = blockIdx.x * blockDim.x + threadIdx.x;
  if (i >= B_N) return;
  int e = expert[i];
  int slot = atomicAdd(&hdr[24 + e], 1);
  idx[slot] = i;
}

// split all weights into bf16 hi/lo planes in ws
__global__ void k_wsplit(const float* __restrict__ W1, const float* __restrict__ W2,
                         const float* __restrict__ W3, const float* __restrict__ W4,
                         unsigned short* __restrict__ wh, unsigned short* __restrict__ wl) {
  for (int i = blockIdx.x * blockDim.x + threadIdx.x; i < W_ELEMS;
       i += gridDim.x * blockDim.x) {
    float f;
    if (i < S_W1) f = W1[i];
    else if (i < S_W1 + S_W2) f = W2[i - S_W1];
    else if (i < S_W1 + S_W2 + S_W3) f = W3[i - S_W1 - S_W2];
    else f = W4[i - S_W1 - S_W2 - S_W3];
    unsigned short h = f2bf(f);
    wh[i] = h;
    wl[i] = f2bf(f - bf2f(h));
  }
}

// ---------------- fused MLP ----------------

__device__ __forceinline__ void cvt8(const float* __restrict__ p, bf16x8* h, bf16x8* l) {
  float4 A = *(const float4*)p;
  float4 Bv = *(const float4*)(p + 4);
  float f[8] = {A.x, A.y, A.z, A.w, Bv.x, Bv.y, Bv.z, Bv.w};
  bf16x8 hv, lv;
#pragma unroll
  for (int i = 0; i < 8; ++i) {
    unsigned short hb = f2bf(f[i]);
    hv[i] = (short)hb;
    lv[i] = (short)f2bf(f[i] - bf2f(hb));
  }
  *h = hv;
  *l = lv;
}

template <bool PRE>
__device__ __forceinline__ void wfrag(const float* wf, const unsigned short* wh,
                                      const unsigned short* wlp, int kb, bf16x8* h, bf16x8* l) {
  if constexpr (PRE) {
    *h = *(const bf16x8*)(wh + kb);
    *l = *(const bf16x8*)(wlp + kb);
  } else {
    cvt8(wf + kb, h, l);
  }
}

__device__ __forceinline__ bf16x8 ldsf(const char* lds, int off, int row, int stride, int bcol) {
  return *(const bf16x8*)(lds + off + row * stride + (bcol ^ ((row & 7) << 4)));
}

template <bool PRE>
__launch_bounds__(THREADS, 4)
__global__ void k_mlp(const float* __restrict__ x,
                      const float* __restrict__ W1, const float* __restrict__ b1,
                      const float* __restrict__ W2, const float* __restrict__ b2,
                      const float* __restrict__ W3, const float* __restrict__ b3,
                      const float* __restrict__ W4, const float* __restrict__ b4,
                      const int* __restrict__ hdr, const int* __restrict__ idx,
                      const unsigned short* __restrict__ wsh,
                      const unsigned short* __restrict__ wsl,
                      float* __restrict__ out) {
  __shared__ __align__(16) char lds[LDS_BYTES];

  // bijective XCD swizzle on [0, 520): consecutive tile ids stay on one XCD
  int b = blockIdx.x;
  int bswz = (b & 7) * (NTILE_MAX / 8) + (b >> 3);

  const int* counts = hdr + 8;
  int e = -1, tile = 0, base = 0, ne = 0;
  {
    int acc = 0, off = 0;
    for (int ee = 0; ee < E_N; ++ee) {
      int n = counts[ee];
      int nt = (n + TILE - 1) / TILE;
      if (bswz < acc + nt) { e = ee; tile = bswz - acc; ne = n; base = off; break; }
      acc += nt; off += n;
    }
  }
  if (e < 0) return;
  const int rvalid = min(TILE, ne - tile * TILE);
  const int row0 = base + tile * TILE;

  const int t = threadIdx.x;
  const int lane = t & 63;
  const int wid = t >> 6;     // 8 waves
  const int lg = lane >> 4;   // k-group 0..3
  const int ln = lane & 15;

  // ---- stage x tile as hi/lo bf16 planes (XOR-swizzled) ----
  const float4* x4 = (const float4*)x;
  for (int u = t; u < TILE * (D_IN / 4); u += THREADS) {  // 4096
    int s = u >> 7;
    int c4 = u & 127;
    float4 v = make_float4(0.f, 0.f, 0.f, 0.f);
    if (s < rvalid) v = x4[idx[row0 + s] * (D_IN / 4) + c4];
    unsigned short h[4], l[4];
#pragma unroll
    for (int i = 0; i < 4; ++i) {
      float fv = (&v.x)[i];
      h[i] = f2bf(fv);
      l[i] = f2bf(fv - bf2f(h[i]));
    }
    int bcol = c4 * 8;
    int sw = (s & 7) << 4;
    *(ushort4*)(lds + XH_OFF + s * 1024 + (bcol ^ sw)) = make_ushort4(h[0], h[1], h[2], h[3]);
    *(ushort4*)(lds + XL_OFF + s * 1024 + (bcol ^ sw)) = make_ushort4(l[0], l[1], l[2], l[3]);
  }
  __syncthreads();

  // L2 persistent accumulator: wave covers cols wid*32..wid*32+31, rows 0..31
  f32x4 acc2[2][2];
#pragma unroll
  for (int m = 0; m < 2; ++m)
#pragma unroll
    for (int nr = 0; nr < 2; ++nr) acc2[m][nr] = (f32x4){0.f, 0.f, 0.f, 0.f};

  const int n2a = wid * 32 + ln;
  const int n2b = n2a + 16;

  // ---- 4 panels: L1 (128 cols) then L2 partial-K ----
  for (int p = 0; p < 4; ++p) {
    // L1: wave computes cols n1, rows 0..31 (m_rep=2)
    f32x4 acc1[2];
    acc1[0] = (f32x4){0.f, 0.f, 0.f, 0.f};
    acc1[1] = (f32x4){0.f, 0.f, 0.f, 0.f};
    const int n1 = p * 128 + wid * 16 + ln;
    const float* w1f = W1 + (long)e * (D_H1 * D_IN) + (long)n1 * D_IN;
    const unsigned short* w1h = wsh + O_W1 + (long)e * (D_H1 * D_IN) + (long)n1 * D_IN;
    const unsigned short* w1l = wsl + O_W1 + (long)e * (D_H1 * D_IN) + (long)n1 * D_IN;

    for (int kc = 0; kc < 16; ++kc) {
      int kb = kc * 32 + 8 * lg;
      bf16x8 wh, wl;
      wfrag<PRE>(w1f, w1h, w1l, kb, &wh, &wl);
      bf16x8 ah[2], al[2];
#pragma unroll
      for (int m = 0; m < 2; ++m) {
        int rr = m * 16 + ln;
        ah[m] = ldsf(lds, XH_OFF, rr, 1024, kc * 64 + lg * 16);
        al[m] = ldsf(lds, XL_OFF, rr, 1024, kc * 64 + lg * 16);
      }
#pragma unroll
      for (int m = 0; m < 2; ++m) acc1[m] = MFMA(ah[m], wh, acc1[m]);
#pragma unroll
      for (int m = 0; m < 2; ++m) acc1[m] = MFMA(al[m], wh, acc1[m]);
#pragma unroll
      for (int m = 0; m < 2; ++m) acc1[m] = MFMA(ah[m], wl, acc1[m]);
    }
    float bias1 = b1[e * D_H1 + n1];
    int colb = (wid * 16 + ln) * 2;
#pragma unroll
    for (int m = 0; m < 2; ++m)
#pragma unroll
      for (int j = 0; j < 4; ++j) {
        float v = acc1[m][j] + bias1;
        v = v > 0.f ? v : 0.f;
        int rw = m * 16 + lg * 4 + j;
        *(unsigned short*)(lds + H1P_OFF + rw * 256 + (colb ^ ((rw & 7) << 4))) = f2bf(v);
      }
    __syncthreads();

    // L2 partial-K over this panel (h1 is bf16-only: 2 products)
    const float* w2fa = W2 + (long)e * (D_H2 * D_H1) + (long)n2a * D_H1;
    const float* w2fb = W2 + (long)e * (D_H2 * D_H1) + (long)n2b * D_H1;
    const unsigned short* w2ha = wsh + O_W2 + (long)e * (D_H2 * D_H1) + (long)n2a * D_H1;
    const unsigned short* w2la = wsl + O_W2 + (long)e * (D_H2 * D_H1) + (long)n2a * D_H1;
    const unsigned short* w2hb = wsh + O_W2 + (long)e * (D_H2 * D_H1) + (long)n2b * D_H1;
    const unsigned short* w2lb = wsl + O_W2 + (long)e * (D_H2 * D_H1) + (long)n2b * D_H1;
#pragma unroll
    for (int kc = 0; kc < 4; ++kc) {
      int kb = p * 128 + kc * 32 + 8 * lg;
      bf16x8 wha, wla, whb, wlb;
      wfrag<PRE>(w2fa, w2ha, w2la, kb, &wha, &wla);
      wfrag<PRE>(w2fb, w2hb, w2lb, kb, &whb, &wlb);
#pragma unroll
      for (int m = 0; m < 2; ++m) {
        bf16x8 a = ldsf(lds, H1P_OFF, m * 16 + ln, 256, kc * 64 + lg * 16);
        acc2[m][0] = MFMA(a, wha, acc2[m][0]);
        acc2[m][0] = MFMA(a, wla, acc2[m][0]);
        acc2[m][1] = MFMA(a, whb, acc2[m][1]);
        acc2[m][1] = MFMA(a, wlb, acc2[m][1]);
      }
    }
    __syncthreads();
  }

  // ---- L2 epilogue -> h2 hi/lo planes (overwrites x region) ----
  {
    float biasA = b2[e * D_H2 + n2a];
    float biasB = b2[e * D_H2 + n2b];
#pragma unroll
    for (int m = 0; m < 2; ++m)
#pragma unroll
      for (int nr = 0; nr < 2; ++nr) {
        float bias = nr ? biasB : biasA;
        int cb = (wid * 32 + nr * 16 + ln) * 2;
#pragma unroll
        for (int j = 0; j < 4; ++j) {
          float v = acc2[m][nr][j] + bias;
          v = v > 0.f ? v : 0.f;
          unsigned short hb = f2bf(v);
          unsigned short lb = f2bf(v - bf2f(hb));
          int rw = m * 16 + lg * 4 + j;
          int sw2 = (rw & 7) << 4;
          *(unsigned short*)(lds + H2H_OFF + rw * 512 + (cb ^ sw2)) = hb;
          *(unsigned short*)(lds + H2L_OFF + rw * 512 + (cb ^ sw2)) = lb;
        }
      }
  }
  __syncthreads();

  // ---- L3: 256 -> 128, full split (3 products) ----
  f32x4 acc3[2];
  acc3[0] = (f32x4){0.f, 0.f, 0.f, 0.f};
  acc3[1] = (f32x4){0.f, 0.f, 0.f, 0.f};
  const int n3 = wid * 16 + ln;
  {
    const float* w3f = W3 + (long)e * (D_H3 * D_H2) + (long)n3 * D_H2;
    const unsigned short* w3h = wsh + O_W3 + (long)e * (D_H3 * D_H2) + (long)n3 * D_H2;
    const unsigned short* w3l = wsl + O_W3 + (long)e * (D_H3 * D_H2) + (long)n3 * D_H2;
#pragma unroll
    for (int kc = 0; kc < 8; ++kc) {
      int kb = kc * 32 + 8 * lg;
      bf16x8 wh, wl;
      wfrag<PRE>(w3f, w3h, w3l, kb, &wh, &wl);
#pragma unroll
      for (int m = 0; m < 2; ++m) {
        int rr = m * 16 + ln;
        bf16x8 ah = ldsf(lds, H2H_OFF, rr, 512, kc * 64 + lg * 16);
        bf16x8 al = ldsf(lds, H2L_OFF, rr, 512, kc * 64 + lg * 16);
        acc3[m] = MFMA(ah, wh, acc3[m]);
        acc3[m] = MFMA(al, wh, acc3[m]);
        acc3[m] = MFMA(ah, wl, acc3[m]);
      }
    }
    float bias3 = b3[e * D_H3 + n3];
    int cb = (wid * 16 + ln) * 2;
#pragma unroll
    for (int m = 0; m < 2; ++m)
#pragma unroll
      for (int j = 0; j < 4; ++j) {
        float v = acc3[m][j] + bias3;
        v = v > 0.f ? v : 0.f;
        unsigned short hb = f2bf(v);
        unsigned short lb = f2bf(v - bf2f(hb));
        int rw = m * 16 + lg * 4 + j;
        int sw2 = (rw & 7) << 4;
        *(unsigned short*)(lds + H3H_OFF + rw * 256 + (cb ^ sw2)) = hb;
        *(unsigned short*)(lds + H3L_OFF + rw * 256 + (cb ^ sw2)) = lb;
      }
  }
  __syncthreads();

  // ---- L4 + softmax (waves 0,1; 16 sample rows each) ----
  if (wid < 2) {
    f32x4 a4 = (f32x4){0.f, 0.f, 0.f, 0.f};
    const float* w4f = W4 + (long)e * (D_A * D_H3) + (long)ln * D_H3;
    const unsigned short* w4h = wsh + O_W4 + (long)e * (D_A * D_H3) + (long)ln * D_H3;
    const unsigned short* w4l = wsl + O_W4 + (long)e * (D_A * D_H3) + (long)ln * D_H3;
#pragma unroll
    for (int kc = 0; kc < 4; ++kc) {
      int kb = kc * 32 + 8 * lg;
      bf16x8 wh, wl;
      wfrag<PRE>(w4f, w4h, w4l, kb, &wh, &wl);
      int rr = wid * 16 + ln;
      bf16x8 ah = ldsf(lds, H3H_OFF, rr, 256, kc * 64 + lg * 16);
      bf16x8 al = ldsf(lds, H3L_OFF, rr, 256, kc * 64 + lg * 16);
      a4 = MFMA(ah, wh, a4);
      a4 = MFMA(al, wh, a4);
      a4 = MFMA(ah, wl, a4);
    }
    float bias4 = b4[e * D_A + ln];
#pragma unroll
    for (int j = 0; j < 4; ++j) {
      float v = a4[j] + bias4;
      float mx = v;
      for (int msk = 8; msk >= 1; msk >>= 1) mx = fmaxf(mx, __shfl_xor(mx, msk));
      float pe = expf(v - mx);
      float sm = pe;
      for (int msk = 8; msk >= 1; msk >>= 1) sm += __shfl_xor(sm, msk);
      int rl = wid * 16 + lg * 4 + j;
      if (rl < rvalid) out[idx[row0 + rl] * D_A + ln] = pe / sm;
    }
  }
}

// ---------------- host ----------------

extern "C" void kernel_launch(void* const* d_in, const int* in_sizes, int n_in,
                              void* d_out, int out_size, void* d_ws, size_t ws_size,
                              hipStream_t stream) {
  const float* x  = (const float*)d_in[0];
  const int* pos  = (const int*)d_in[1];
  const float* W1 = (const float*)d_in[2];
  const float* b1 = (const float*)d_in[3];
  const float* W2 = (const float*)d_in[4];
  const float* b2 = (const float*)d_in[5];
  const float* W3 = (const float*)d_in[6];
  const float* b3 = (const float*)d_in[7];
  const float* W4 = (const float*)d_in[8];
  const float* b4 = (const float*)d_in[9];
  float* out = (float*)d_out;

  int* hdr = (int*)d_ws;
  int* idx = hdr + IDX_OFF;
  int* expert = hdr + EXP_OFF;
  unsigned short* wsh = (unsigned short*)((char*)d_ws + WB_OFF);
  unsigned short* wsl = wsh + W_ELEMS;

  hipLaunchKernelGGL(k_init, dim3(1), dim3(64), 0, stream, pos, hdr);
  hipLaunchKernelGGL(k_count, dim3(B_N / 256), dim3(256), 0, stream, pos, hdr, expert);
  hipLaunchKernelGGL(k_scan, dim3(1), dim3(1), 0, stream, hdr);
  hipLaunchKernelGGL(k_scatter, dim3(B_N / 256), dim3(256), 0, stream, expert, hdr, idx);

  bool pre = ws_size >= WS_NEED;
  if (pre) {
    hipLaunchKernelGGL(k_wsplit, dim3(1024), dim3(256), 0, stream, W1, W2, W3, W4, wsh, wsl);
    hipLaunchKernelGGL(k_mlp<true>, dim3(NTILE_MAX), dim3(THREADS), 0, stream,
                       x, W1, b1, W2, b2, W3, b3, W4, b4, hdr, idx, wsh, wsl, out);
  } else {
    hipLaunchKernelGGL(k_mlp<false>, dim3(NTILE_MAX), dim3(THREADS), 0, stream,
                       x, W1, b1, W2, b2, W3, b3, W4, b4, hdr, idx, wsh, wsl, out);
  }
}

// Round 3
// 110.126 us; speedup vs baseline: 4.4697x; 2.6865x over previous
//
#include <hip/hip_runtime.h>

typedef _Float16 f16;
typedef __attribute__((ext_vector_type(8))) _Float16 f16x8;
typedef __attribute__((ext_vector_type(4))) _Float16 f16x4;
typedef __attribute__((ext_vector_type(4))) float f32x4;

#define MFMA16(a, b, c) __builtin_amdgcn_mfma_f32_16x16x32_f16(a, b, c, 0, 0, 0)

#define B_N 16384
#define E_N 9
#define TILE 32
#define NTILE_MAX (B_N / TILE + E_N - 1)  // 520 = 8*65, XCD-swizzle exact
#define THREADS 512

#define D_IN 512
#define D_H1 512
#define D_H2 256
#define D_H3 128
#define D_A 16

// fp16 weight plane element offsets
#define O_W1 0
#define O_W2 2359296
#define O_W3 3538944
#define O_W4 3833856
#define W_ELEMS 3852288
#define S_W1 2359296
#define S_W2 1179648
#define S_W3 294912

// ws layout
#define IDX_OFF 64
#define WP_OFF 131584  // byte offset of fp16 weight plane
#define WS_NEED (WP_OFF + (size_t)W_ELEMS * 2)

// LDS layout (bytes)
#define XS_OFF 0       // x fp16 [32][512], stride 1024
#define H1_OFF 32768   // h1 fp16 [32][512], stride 1024
#define H2_OFF 0       // h2 fp16 [32][256], stride 512 (overlays XS)
#define H3_OFF 16384   // h3 fp16 [32][128], stride 256 (overlays XS)
#define LDS_BYTES 65536

// ---------------- bucketing: one block does detect+count+scan+scatter ----------------

__global__ void k_bucket(const int* __restrict__ pos, int* __restrict__ hdr,
                         int* __restrict__ idx) {
  __shared__ int cnt[E_N], cur[E_N];
  __shared__ int flag_s;
  const int t = threadIdx.x;  // 1024 threads
  if (t < E_N) cnt[t] = 0;
  if (t == 0) {
    int nz = 0;
    for (int i = 0; i < 64; ++i) nz |= pos[2 * i + 1];
    flag_s = (nz == 0) ? 1 : 0;  // int64 layout if high words all zero
  }
  __syncthreads();
  const bool f64 = flag_s != 0;
  int e[16];
#pragma unroll
  for (int k = 0; k < 16; ++k) {
    int i = k * 1024 + t;
    long long v = f64 ? ((const long long*)pos)[i] : (long long)pos[i];
    v = v < 0 ? 0 : (v > 8 ? 8 : v);
    e[k] = (int)v;
    atomicAdd(&cnt[e[k]], 1);
  }
  __syncthreads();
  if (t == 0) {
    int acc = 0;
    for (int ee = 0; ee < E_N; ++ee) { cur[ee] = acc; acc += cnt[ee]; }
  }
  if (t < E_N) hdr[8 + t] = cnt[t];
  __syncthreads();
#pragma unroll
  for (int k = 0; k < 16; ++k) {
    int i = k * 1024 + t;
    int slot = atomicAdd(&cur[e[k]], 1);
    idx[slot] = i;
  }
}

// ---------------- weight convert fp32 -> fp16 plane ----------------

__global__ void k_wcvt(const float* __restrict__ W1, const float* __restrict__ W2,
                       const float* __restrict__ W3, const float* __restrict__ W4,
                       f16* __restrict__ wp) {
  const int NU = W_ELEMS / 8;
  for (int u = blockIdx.x * blockDim.x + threadIdx.x; u < NU;
       u += gridDim.x * blockDim.x) {
    long i = (long)u * 8;
    const float* src;
    long off;
    if (i < S_W1) { src = W1; off = i; }
    else if (i < S_W1 + S_W2) { src = W2; off = i - S_W1; }
    else if (i < S_W1 + S_W2 + S_W3) { src = W3; off = i - S_W1 - S_W2; }
    else { src = W4; off = i - S_W1 - S_W2 - S_W3; }
    float4 a = *(const float4*)(src + off);
    float4 b = *(const float4*)(src + off + 4);
    f16x8 h;
    h[0] = (f16)a.x; h[1] = (f16)a.y; h[2] = (f16)a.z; h[3] = (f16)a.w;
    h[4] = (f16)b.x; h[5] = (f16)b.y; h[6] = (f16)b.z; h[7] = (f16)b.w;
    *(f16x8*)(wp + i) = h;
  }
}

// ---------------- fused MLP ----------------

template <bool PRE>
__device__ __forceinline__ f16x8 wload(const f16* wph, const float* wf) {
  if constexpr (PRE) {
    return *(const f16x8*)wph;
  } else {
    float4 a = *(const float4*)wf;
    float4 b = *(const float4*)(wf + 4);
    f16x8 h;
    h[0] = (f16)a.x; h[1] = (f16)a.y; h[2] = (f16)a.z; h[3] = (f16)a.w;
    h[4] = (f16)b.x; h[5] = (f16)b.y; h[6] = (f16)b.z; h[7] = (f16)b.w;
    return h;
  }
}

__device__ __forceinline__ f16x8 ldsA(const char* lds, int off, int row, int strideB,
                                      int bcol) {
  return *(const f16x8*)(lds + off + row * strideB + (bcol ^ ((row & 7) << 4)));
}

template <bool PRE>
__launch_bounds__(THREADS, 4)
__global__ void k_mlp(const float* __restrict__ x,
                      const float* __restrict__ W1, const float* __restrict__ b1,
                      const float* __restrict__ W2, const float* __restrict__ b2,
                      const float* __restrict__ W3, const float* __restrict__ b3,
                      const float* __restrict__ W4, const float* __restrict__ b4,
                      const int* __restrict__ hdr, const int* __restrict__ idx,
                      const f16* __restrict__ wp, float* __restrict__ out) {
  __shared__ __align__(16) char lds[LDS_BYTES];

  // bijective XCD swizzle on [0,520): 520 = 8*65
  int b = blockIdx.x;
  int bswz = (b & 7) * (NTILE_MAX / 8) + (b >> 3);

  const int* counts = hdr + 8;
  int e = -1, tile = 0, base = 0, ne = 0;
  {
    int acc = 0, off = 0;
    for (int ee = 0; ee < E_N; ++ee) {
      int n = counts[ee];
      int nt = (n + TILE - 1) / TILE;
      if (bswz < acc + nt) { e = ee; tile = bswz - acc; ne = n; base = off; break; }
      acc += nt; off += n;
    }
  }
  if (e < 0) return;
  const int rvalid = min(TILE, ne - tile * TILE);
  const int row0 = base + tile * TILE;

  const int t = threadIdx.x;
  const int lane = t & 63;
  const int wid = t >> 6;   // 8 waves
  const int lg = lane >> 4; // k-group 0..3
  const int ln = lane & 15;

  // ---- stage x tile as fp16 (XOR-swizzled, 16B granularity) ----
  const float4* x4 = (const float4*)x;
  for (int u = t; u < TILE * (D_IN / 4); u += THREADS) {  // 4096
    int s = u >> 7;
    int c4 = u & 127;
    float4 v = make_float4(0.f, 0.f, 0.f, 0.f);
    if (s < rvalid) v = x4[(long)idx[row0 + s] * (D_IN / 4) + c4];
    f16x4 h;
    h[0] = (f16)v.x; h[1] = (f16)v.y; h[2] = (f16)v.z; h[3] = (f16)v.w;
    int bcol = c4 * 8;
    *(f16x4*)(lds + XS_OFF + s * 1024 + (bcol ^ ((s & 7) << 4))) = h;
  }
  __syncthreads();

  // ---------------- L1: [32x512] = x[32x512] @ W1^T, fp16 ----------------
  {
    f32x4 acc[2][4];
#pragma unroll
    for (int m = 0; m < 2; ++m)
#pragma unroll
      for (int r = 0; r < 4; ++r) acc[m][r] = (f32x4){0.f, 0.f, 0.f, 0.f};

    const f16* wh = wp + O_W1 + (long)e * (D_H1 * D_IN);
    const float* wf = W1 + (long)e * (D_H1 * D_IN);
    const f16* wc[4];
    const float* wcf[4];
#pragma unroll
    for (int r = 0; r < 4; ++r) {
      long nn = wid * 64 + r * 16 + ln;
      wc[r] = wh + nn * D_IN;
      wcf[r] = wf + nn * D_IN;
    }
    f16x8 Bc[4], Bn[4], Ac[2], An[2];
    {
      int kb = lg * 8;
#pragma unroll
      for (int r = 0; r < 4; ++r) Bc[r] = wload<PRE>(wc[r] + kb, wcf[r] + kb);
      Ac[0] = ldsA(lds, XS_OFF, ln, 1024, lg * 16);
      Ac[1] = ldsA(lds, XS_OFF, 16 + ln, 1024, lg * 16);
    }
#pragma unroll
    for (int kc = 0; kc < 16; ++kc) {
      if (kc < 15) {
        int kb = (kc + 1) * 32 + lg * 8;
#pragma unroll
        for (int r = 0; r < 4; ++r) Bn[r] = wload<PRE>(wc[r] + kb, wcf[r] + kb);
        An[0] = ldsA(lds, XS_OFF, ln, 1024, (kc + 1) * 64 + lg * 16);
        An[1] = ldsA(lds, XS_OFF, 16 + ln, 1024, (kc + 1) * 64 + lg * 16);
      }
#pragma unroll
      for (int m = 0; m < 2; ++m)
#pragma unroll
        for (int r = 0; r < 4; ++r) acc[m][r] = MFMA16(Ac[m], Bc[r], acc[m][r]);
#pragma unroll
      for (int r = 0; r < 4; ++r) Bc[r] = Bn[r];
      Ac[0] = An[0]; Ac[1] = An[1];
    }
#pragma unroll
    for (int r = 0; r < 4; ++r) {
      int n = wid * 64 + r * 16 + ln;
      float bias = b1[e * D_H1 + n];
      int cb = n * 2;
#pragma unroll
      for (int m = 0; m < 2; ++m)
#pragma unroll
        for (int j = 0; j < 4; ++j) {
          float v = acc[m][r][j] + bias;
          v = v > 0.f ? v : 0.f;
          int rw = m * 16 + lg * 4 + j;
          *(f16*)(lds + H1_OFF + rw * 1024 + (cb ^ ((rw & 7) << 4))) = (f16)v;
        }
    }
  }
  __syncthreads();

  // ---------------- L2: [32x256] = h1[32x512] @ W2^T ----------------
  {
    f32x4 acc[2][2];
#pragma unroll
    for (int m = 0; m < 2; ++m)
#pragma unroll
      for (int r = 0; r < 2; ++r) acc[m][r] = (f32x4){0.f, 0.f, 0.f, 0.f};

    const f16* wh = wp + O_W2 + (long)e * (D_H2 * D_H1);
    const float* wf = W2 + (long)e * (D_H2 * D_H1);
    const f16* wc[2];
    const float* wcf[2];
#pragma unroll
    for (int r = 0; r < 2; ++r) {
      long nn = wid * 32 + r * 16 + ln;
      wc[r] = wh + nn * D_H1;
      wcf[r] = wf + nn * D_H1;
    }
    f16x8 Bc[2], Bn[2], Ac[2], An[2];
    {
      int kb = lg * 8;
#pragma unroll
      for (int r = 0; r < 2; ++r) Bc[r] = wload<PRE>(wc[r] + kb, wcf[r] + kb);
      Ac[0] = ldsA(lds, H1_OFF, ln, 1024, lg * 16);
      Ac[1] = ldsA(lds, H1_OFF, 16 + ln, 1024, lg * 16);
    }
#pragma unroll
    for (int kc = 0; kc < 16; ++kc) {
      if (kc < 15) {
        int kb = (kc + 1) * 32 + lg * 8;
#pragma unroll
        for (int r = 0; r < 2; ++r) Bn[r] = wload<PRE>(wc[r] + kb, wcf[r] + kb);
        An[0] = ldsA(lds, H1_OFF, ln, 1024, (kc + 1) * 64 + lg * 16);
        An[1] = ldsA(lds, H1_OFF, 16 + ln, 1024, (kc + 1) * 64 + lg * 16);
      }
#pragma unroll
      for (int m = 0; m < 2; ++m)
#pragma unroll
        for (int r = 0; r < 2; ++r) acc[m][r] = MFMA16(Ac[m], Bc[r], acc[m][r]);
#pragma unroll
      for (int r = 0; r < 2; ++r) Bc[r] = Bn[r];
      Ac[0] = An[0]; Ac[1] = An[1];
    }
#pragma unroll
    for (int r = 0; r < 2; ++r) {
      int n = wid * 32 + r * 16 + ln;
      float bias = b2[e * D_H2 + n];
      int cb = n * 2;
#pragma unroll
      for (int m = 0; m < 2; ++m)
#pragma unroll
        for (int j = 0; j < 4; ++j) {
          float v = acc[m][r][j] + bias;
          v = v > 0.f ? v : 0.f;
          int rw = m * 16 + lg * 4 + j;
          *(f16*)(lds + H2_OFF + rw * 512 + (cb ^ ((rw & 7) << 4))) = (f16)v;
        }
    }
  }
  __syncthreads();

  // ---------------- L3: [32x128] = h2[32x256] @ W3^T ----------------
  {
    f32x4 acc[2];
    acc[0] = (f32x4){0.f, 0.f, 0.f, 0.f};
    acc[1] = (f32x4){0.f, 0.f, 0.f, 0.f};
    const int n = wid * 16 + ln;
    const f16* wc = wp + O_W3 + (long)e * (D_H3 * D_H2) + (long)n * D_H2;
    const float* wcf = W3 + (long)e * (D_H3 * D_H2) + (long)n * D_H2;
    f16x8 Bc, Bn, Ac[2], An[2];
    {
      int kb = lg * 8;
      Bc = wload<PRE>(wc + kb, wcf + kb);
      Ac[0] = ldsA(lds, H2_OFF, ln, 512, lg * 16);
      Ac[1] = ldsA(lds, H2_OFF, 16 + ln, 512, lg * 16);
    }
#pragma unroll
    for (int kc = 0; kc < 8; ++kc) {
      if (kc < 7) {
        int kb = (kc + 1) * 32 + lg * 8;
        Bn = wload<PRE>(wc + kb, wcf + kb);
        An[0] = ldsA(lds, H2_OFF, ln, 512, (kc + 1) * 64 + lg * 16);
        An[1] = ldsA(lds, H2_OFF, 16 + ln, 512, (kc + 1) * 64 + lg * 16);
      }
#pragma unroll
      for (int m = 0; m < 2; ++m) acc[m] = MFMA16(Ac[m], Bc, acc[m]);
      Bc = Bn; Ac[0] = An[0]; Ac[1] = An[1];
    }
    float bias = b3[e * D_H3 + n];
    int cb = n * 2;
#pragma unroll
    for (int m = 0; m < 2; ++m)
#pragma unroll
      for (int j = 0; j < 4; ++j) {
        float v = acc[m][j] + bias;
        v = v > 0.f ? v : 0.f;
        int rw = m * 16 + lg * 4 + j;
        *(f16*)(lds + H3_OFF + rw * 256 + (cb ^ ((rw & 7) << 4))) = (f16)v;
      }
  }
  __syncthreads();

  // ---------------- L4 + softmax (waves 0,1) ----------------
  if (wid < 2) {
    f32x4 a4 = (f32x4){0.f, 0.f, 0.f, 0.f};
    const f16* wc = wp + O_W4 + (long)e * (D_A * D_H3) + (long)ln * D_H3;
    const float* wcf = W4 + (long)e * (D_A * D_H3) + (long)ln * D_H3;
#pragma unroll
    for (int kc = 0; kc < 4; ++kc) {
      int kb = kc * 32 + lg * 8;
      f16x8 Bv = wload<PRE>(wc + kb, wcf + kb);
      f16x8 Av = ldsA(lds, H3_OFF, wid * 16 + ln, 256, kc * 64 + lg * 16);
      a4 = MFMA16(Av, Bv, a4);
    }
    float bias = b4[e * D_A + ln];
#pragma unroll
    for (int j = 0; j < 4; ++j) {
      float v = a4[j] + bias;
      float mx = v;
      for (int msk = 8; msk >= 1; msk >>= 1) mx = fmaxf(mx, __shfl_xor(mx, msk));
      float pe = expf(v - mx);
      float sm = pe;
      for (int msk = 8; msk >= 1; msk >>= 1) sm += __shfl_xor(sm, msk);
      int rl = wid * 16 + lg * 4 + j;
      if (rl < rvalid) out[(long)idx[row0 + rl] * D_A + ln] = pe / sm;
    }
  }
}

// ---------------- host ----------------

extern "C" void kernel_launch(void* const* d_in, const int* in_sizes, int n_in,
                              void* d_out, int out_size, void* d_ws, size_t ws_size,
                              hipStream_t stream) {
  const float* x  = (const float*)d_in[0];
  const int* pos  = (const int*)d_in[1];
  const float* W1 = (const float*)d_in[2];
  const float* b1 = (const float*)d_in[3];
  const float* W2 = (const float*)d_in[4];
  const float* b2 = (const float*)d_in[5];
  const float* W3 = (const float*)d_in[6];
  const float* b3 = (const float*)d_in[7];
  const float* W4 = (const float*)d_in[8];
  const float* b4 = (const float*)d_in[9];
  float* out = (float*)d_out;

  int* hdr = (int*)d_ws;
  int* idx = hdr + IDX_OFF;
  f16* wp = (f16*)((char*)d_ws + WP_OFF);

  hipLaunchKernelGGL(k_bucket, dim3(1), dim3(1024), 0, stream, pos, hdr, idx);

  bool pre = ws_size >= WS_NEED;
  if (pre) {
    hipLaunchKernelGGL(k_wcvt, dim3(1882), dim3(256), 0, stream, W1, W2, W3, W4, wp);
    hipLaunchKernelGGL(k_mlp<true>, dim3(NTILE_MAX), dim3(THREADS), 0, stream,
                       x, W1, b1, W2, b2, W3, b3, W4, b4, hdr, idx, wp, out);
  } else {
    hipLaunchKernelGGL(k_mlp<false>, dim3(NTILE_MAX), dim3(THREADS), 0, stream,
                       x, W1, b1, W2, b2, W3, b3, W4, b4, hdr, idx, wp, out);
  }
}

// Round 5
// 79.797 us; speedup vs baseline: 6.1686x; 1.3801x over previous
//
#include <hip/hip_runtime.h>

typedef _Float16 f16;
typedef __attribute__((ext_vector_type(8))) _Float16 f16x8;
typedef __attribute__((ext_vector_type(4))) _Float16 f16x4;
typedef __attribute__((ext_vector_type(4))) float f32x4;

#define MFMA16(a, b, c) __builtin_amdgcn_mfma_f32_16x16x32_f16(a, b, c, 0, 0, 0)

#define B_N 16384
#define E_N 9
#define TILE 32
#define NTILE_MAX 520  // = 8*65, XCD swizzle exact
#define THREADS 512

#define D_IN 512
#define D_H1 512
#define D_H2 256
#define D_H3 128
#define D_A 16

// chunked fp16 weight plane (byte offsets). Chunk = [32n x 64k] = 4KB (L1/L2),
// [16n x 64k] = 2KB (L3), plain [16 x 128] (L4). XOR-swizzle baked into image:
// image byte (nl, pb) holds logical k-byte pb ^ ((nl&7)<<4) of row nl.
#define O1B 0
#define O2B 4718592    // 9 * 16nb * 8kb * 4096
#define O3B 7077888    // +9 * 8nb * 8kb * 4096
#define O4B 7667712    // +9 * 8nb * 4kb * 2048
#define WPL_BYTES 7704576
#define WSLOTS (WPL_BYTES / 16)   // 481536 = 1881 * 256

#define IDX_OFF 64
#define WP_OFF 131584
#define WS_NEED (WP_OFF + (size_t)WPL_BYTES)

// LDS (bytes)
#define XS_OFF 0        // x fp16 [32][512] stride 1024, swz ((row&15)<<4)
#define H1_OFF 32768    // h1 fp16 [32][512] stride 1024
#define RING_OFF 65536  // 8 waves * 2 slots * 4KB
#define H2_OFF 0        // h2 [32][256] stride 512 (overlays x)
#define H3_OFF 16384    // h3 [32][128] stride 256 (overlays x)
#define LDS_BYTES 131072

// ---------------- bucketing ----------------

__global__ void k_bucket(const int* __restrict__ pos, int* __restrict__ hdr,
                         int* __restrict__ idx) {
  __shared__ int cnt[E_N], cur[E_N];
  __shared__ int flag_s;
  const int t = threadIdx.x;  // 1024
  if (t < E_N) cnt[t] = 0;
  if (t == 0) {
    int nz = 0;
    for (int i = 0; i < 64; ++i) nz |= pos[2 * i + 1];
    flag_s = (nz == 0) ? 1 : 0;  // int64 layout if all high words zero
  }
  __syncthreads();
  const bool f64 = flag_s != 0;
  int e[16];
#pragma unroll
  for (int k = 0; k < 16; ++k) {
    int i = k * 1024 + t;
    long long v = f64 ? ((const long long*)pos)[i] : (long long)pos[i];
    v = v < 0 ? 0 : (v > 8 ? 8 : v);
    e[k] = (int)v;
    atomicAdd(&cnt[e[k]], 1);
  }
  __syncthreads();
  if (t == 0) {
    int acc = 0;
    for (int ee = 0; ee < E_N; ++ee) { cur[ee] = acc; acc += cnt[ee]; }
  }
  if (t < E_N) hdr[8 + t] = cnt[t];
  __syncthreads();
#pragma unroll
  for (int k = 0; k < 16; ++k) {
    int i = k * 1024 + t;
    int slot = atomicAdd(&cur[e[k]], 1);
    idx[slot] = i;
  }
}

// ---------------- weight convert fp32 -> chunked swizzled fp16 plane ----------------
// Decode is the exact inverse of bfrag/load4: chunk rows of 128B, 16B slots,
// logical k-byte = (r4 & 127) ^ ((nl & 7) << 4).

__global__ void k_wcvt(const float* __restrict__ W1, const float* __restrict__ W2,
                       const float* __restrict__ W3, const float* __restrict__ W4,
                       char* __restrict__ wp) {
  int slot = blockIdx.x * 256 + threadIdx.x;
  if (slot >= WSLOTS) return;
  long addr = (long)slot << 4;
  const float* src;
  if (addr < O2B) {
    long rel = addr;
    int e = (int)(rel >> 19);
    int r2 = (int)(rel & 524287);
    int nb = r2 >> 15;
    int r3 = r2 & 32767;
    int kb = r3 >> 12;
    int r4 = r3 & 4095;                       // within 4KB chunk, slot-aligned
    int nl = r4 >> 7;                         // 32 rows x 128B
    int kbyt = (r4 & 127) ^ ((nl & 7) << 4);  // logical k-byte
    int n = nb * 32 + nl;
    int k = kb * 64 + (kbyt >> 1);
    src = W1 + ((long)e * D_H1 + n) * D_IN + k;
  } else if (addr < O3B) {
    long rel = addr - O2B;
    int e = (int)(rel >> 18);
    int r2 = (int)(rel & 262143);
    int nb = r2 >> 15;
    int r3 = r2 & 32767;
    int kb = r3 >> 12;
    int r4 = r3 & 4095;
    int nl = r4 >> 7;
    int kbyt = (r4 & 127) ^ ((nl & 7) << 4);
    int n = nb * 32 + nl;
    int k = kb * 64 + (kbyt >> 1);
    src = W2 + ((long)e * D_H2 + n) * D_H1 + k;
  } else if (addr < O4B) {
    long rel = addr - O3B;
    int e = (int)(rel >> 16);
    int r2 = (int)(rel & 65535);
    int nb = r2 >> 13;
    int r3 = r2 & 8191;
    int kb = r3 >> 11;
    int r4 = r3 & 2047;                       // within 2KB chunk
    int nl = r4 >> 7;                         // 16 rows x 128B
    int kbyt = (r4 & 127) ^ ((nl & 7) << 4);
    int n = nb * 16 + nl;
    int k = kb * 64 + (kbyt >> 1);
    src = W3 + ((long)e * D_H3 + n) * D_H2 + k;
  } else {
    long rel = addr - O4B;
    int e = (int)(rel >> 12);
    int r2 = (int)(rel & 4095);
    int s = r2 >> 4, n = s >> 4, k16 = s & 15;
    src = W4 + ((long)e * D_A + n) * D_H3 + k16 * 8;
  }
  float4 a = *(const float4*)src;
  float4 b = *(const float4*)(src + 4);
  f16x8 h;
  h[0] = (f16)a.x; h[1] = (f16)a.y; h[2] = (f16)a.z; h[3] = (f16)a.w;
  h[4] = (f16)b.x; h[5] = (f16)b.y; h[6] = (f16)b.z; h[7] = (f16)b.w;
  *(f16x8*)(wp + addr) = h;
}

// ---------------- fused MLP ----------------

// A-fragment (16x16x32): lane m = rowoff + (l&15), k-bytes q + (l>>4)*16, XOR swz
__device__ __forceinline__ f16x8 afrag(const char* base, int strideB, int rowoff,
                                       int kbytes, int lane) {
  int m = rowoff + (lane & 15);
  int q = kbytes + ((lane >> 4) * 16);
  return *(const f16x8*)(base + m * strideB + (q ^ ((lane & 15) << 4)));
}
// B-fragment from a staged chunk (rows 128B, swizzled image)
__device__ __forceinline__ f16x8 bfrag(const char* slot, int nf, int kc, int lane) {
  int nl = nf * 16 + (lane & 15);
  int q = kc * 64 + ((lane >> 4) * 16);
  return *(const f16x8*)(slot + nl * 128 + (q ^ ((nl & 7) << 4)));
}

__device__ __forceinline__ void load4(f16x8* d, const char* cbase, int lane) {
  const f16x8* g = (const f16x8*)cbase + lane;
  d[0] = g[0]; d[1] = g[64]; d[2] = g[128]; d[3] = g[192];
}
__device__ __forceinline__ void store4(char* slot, const f16x8* s, int lane) {
  f16x8* d = (f16x8*)slot + lane;
  d[0] = s[0]; d[64] = s[1]; d[128] = s[2]; d[192] = s[3];
}
__device__ __forceinline__ void load2(f16x8* d, const char* cbase, int lane) {
  const f16x8* g = (const f16x8*)cbase + lane;
  d[0] = g[0]; d[1] = g[64];
}
__device__ __forceinline__ void store2(char* slot, const f16x8* s, int lane) {
  f16x8* d = (f16x8*)slot + lane;
  d[0] = s[0]; d[64] = s[1];
}

__launch_bounds__(THREADS, 2)
__global__ void k_mlp(const float* __restrict__ x,
                      const float* __restrict__ b1, const float* __restrict__ b2,
                      const float* __restrict__ b3, const float* __restrict__ b4,
                      const int* __restrict__ hdr, const int* __restrict__ idx,
                      const char* __restrict__ wp, float* __restrict__ out) {
  __shared__ __align__(16) char lds[LDS_BYTES];

  int b = blockIdx.x;
  int bswz = (b & 7) * (NTILE_MAX / 8) + (b >> 3);  // bijective, 520 = 8*65

  const int* counts = hdr + 8;
  int e = -1, tile = 0, base = 0, ne = 0;
  {
    int acc = 0, off = 0;
    for (int ee = 0; ee < E_N; ++ee) {
      int n = counts[ee];
      int nt = (n + TILE - 1) / TILE;
      if (bswz < acc + nt) { e = ee; tile = bswz - acc; ne = n; base = off; break; }
      acc += nt; off += n;
    }
  }
  if (e < 0) return;
  const int rvalid = min(TILE, ne - tile * TILE);
  const int row0 = base + tile * TILE;

  const int t = threadIdx.x;
  const int lane = t & 63;
  const int wid = t >> 6;
  const int lg = lane >> 4;
  const int ln = lane & 15;

  const char* wpe1 = wp + O1B + (long)e * 524288;
  const char* wpe2 = wp + O2B + (long)e * 262144;
  const char* wpe3 = wp + O3B + (long)e * 65536;
  const char* wpe4 = wp + O4B + (long)e * 4096;
  char* ring = lds + RING_OFF + wid * 8192;

  f16x8 bufA[4], bufB[4];
  // issue L1 chunk 0 loads before x staging (latency fully hidden)
  load4(bufA, wpe1 + ((long)(wid * 2) << 15), lane);  // nb=wid*2, kb=0

  // ---- stage x tile as fp16, XOR-swizzled ----
  const float4* x4 = (const float4*)x;
  for (int u = t; u < TILE * (D_IN / 4); u += THREADS) {
    int s = u >> 7, c4 = u & 127;
    float4 v = make_float4(0.f, 0.f, 0.f, 0.f);
    if (s < rvalid) v = x4[(long)idx[row0 + s] * (D_IN / 4) + c4];
    f16x4 h;
    h[0] = (f16)v.x; h[1] = (f16)v.y; h[2] = (f16)v.z; h[3] = (f16)v.w;
    *(f16x4*)(lds + XS_OFF + s * 1024 + ((c4 * 8) ^ ((s & 15) << 4))) = h;
  }
  __syncthreads();

  // ---------------- L1: h1[32x512] = x @ W1^T ----------------
  {
    f32x4 acc[2][2];
#pragma unroll
    for (int g = 0; g < 16; ++g) {
      const int nf32 = g >> 3, kb = g & 7;
      f16x8* cur = (g & 1) ? bufB : bufA;
      f16x8* nxt = (g & 1) ? bufA : bufB;
      if (g < 15) {
        int g2 = g + 1;
        load4(nxt, wpe1 + ((long)((wid * 2 + (g2 >> 3)) * 8 + (g2 & 7)) << 12), lane);
      } else {
        load4(nxt, wpe2 + ((long)(wid * 8) << 12), lane);  // L2 chunk 0
      }
      char* slot = ring + (g & 1) * 4096;
      store4(slot, cur, lane);
      if (kb == 0) {
#pragma unroll
        for (int m = 0; m < 2; ++m)
#pragma unroll
          for (int nf = 0; nf < 2; ++nf) acc[m][nf] = (f32x4){0.f, 0.f, 0.f, 0.f};
      }
      __builtin_amdgcn_s_setprio(1);
#pragma unroll
      for (int kc = 0; kc < 2; ++kc) {
        f16x8 A0 = afrag(lds + XS_OFF, 1024, 0, kb * 128 + kc * 64, lane);
        f16x8 A1 = afrag(lds + XS_OFF, 1024, 16, kb * 128 + kc * 64, lane);
        f16x8 B0 = bfrag(slot, 0, kc, lane);
        f16x8 B1 = bfrag(slot, 1, kc, lane);
        acc[0][0] = MFMA16(A0, B0, acc[0][0]);
        acc[0][1] = MFMA16(A0, B1, acc[0][1]);
        acc[1][0] = MFMA16(A1, B0, acc[1][0]);
        acc[1][1] = MFMA16(A1, B1, acc[1][1]);
      }
      __builtin_amdgcn_s_setprio(0);
      if (kb == 7) {
#pragma unroll
        for (int nf = 0; nf < 2; ++nf) {
          int n = wid * 64 + nf32 * 32 + nf * 16 + ln;
          float bias = b1[e * D_H1 + n];
#pragma unroll
          for (int m = 0; m < 2; ++m)
#pragma unroll
            for (int j = 0; j < 4; ++j) {
              float v = acc[m][nf][j] + bias;
              v = v > 0.f ? v : 0.f;
              int rw = m * 16 + lg * 4 + j;
              *(f16*)(lds + H1_OFF + rw * 1024 + ((n * 2) ^ ((rw & 15) << 4))) = (f16)v;
            }
        }
      }
    }
  }
  __syncthreads();

  // ---------------- L2: h2[32x256] = h1 @ W2^T ----------------
  {
    f32x4 acc[2][2];
#pragma unroll
    for (int m = 0; m < 2; ++m)
#pragma unroll
      for (int nf = 0; nf < 2; ++nf) acc[m][nf] = (f32x4){0.f, 0.f, 0.f, 0.f};
#pragma unroll
    for (int g = 0; g < 8; ++g) {
      f16x8* cur = (g & 1) ? bufB : bufA;
      f16x8* nxt = (g & 1) ? bufA : bufB;
      if (g < 7) load4(nxt, wpe2 + ((long)(wid * 8 + g + 1) << 12), lane);
      else load2(nxt, wpe3 + ((long)(wid * 4) << 11), lane);  // L3 chunk 0
      char* slot = ring + (g & 1) * 4096;
      store4(slot, cur, lane);
      __builtin_amdgcn_s_setprio(1);
#pragma unroll
      for (int kc = 0; kc < 2; ++kc) {
        f16x8 A0 = afrag(lds + H1_OFF, 1024, 0, g * 128 + kc * 64, lane);
        f16x8 A1 = afrag(lds + H1_OFF, 1024, 16, g * 128 + kc * 64, lane);
        f16x8 B0 = bfrag(slot, 0, kc, lane);
        f16x8 B1 = bfrag(slot, 1, kc, lane);
        acc[0][0] = MFMA16(A0, B0, acc[0][0]);
        acc[0][1] = MFMA16(A0, B1, acc[0][1]);
        acc[1][0] = MFMA16(A1, B0, acc[1][0]);
        acc[1][1] = MFMA16(A1, B1, acc[1][1]);
      }
      __builtin_amdgcn_s_setprio(0);
    }
#pragma unroll
    for (int nf = 0; nf < 2; ++nf) {
      int n = wid * 32 + nf * 16 + ln;
      float bias = b2[e * D_H2 + n];
#pragma unroll
      for (int m = 0; m < 2; ++m)
#pragma unroll
        for (int j = 0; j < 4; ++j) {
          float v = acc[m][nf][j] + bias;
          v = v > 0.f ? v : 0.f;
          int rw = m * 16 + lg * 4 + j;
          *(f16*)(lds + H2_OFF + rw * 512 + ((n * 2) ^ ((rw & 15) << 4))) = (f16)v;
        }
    }
  }
  __syncthreads();

  // ---------------- L3: h3[32x128] = h2 @ W3^T ----------------
  {
    f32x4 acc3[2];
    acc3[0] = (f32x4){0.f, 0.f, 0.f, 0.f};
    acc3[1] = (f32x4){0.f, 0.f, 0.f, 0.f};
#pragma unroll
    for (int g = 0; g < 4; ++g) {
      f16x8* cur = (g & 1) ? bufB : bufA;
      f16x8* nxt = (g & 1) ? bufA : bufB;
      if (g < 3) load2(nxt, wpe3 + ((long)(wid * 4 + g + 1) << 11), lane);
      char* slot = ring + (g & 1) * 4096;
      store2(slot, cur, lane);
      __builtin_amdgcn_s_setprio(1);
#pragma unroll
      for (int kc = 0; kc < 2; ++kc) {
        f16x8 B0 = bfrag(slot, 0, kc, lane);
#pragma unroll
        for (int m = 0; m < 2; ++m) {
          f16x8 A = afrag(lds + H2_OFF, 512, m * 16, g * 128 + kc * 64, lane);
          acc3[m] = MFMA16(A, B0, acc3[m]);
        }
      }
      __builtin_amdgcn_s_setprio(0);
    }
    int n = wid * 16 + ln;
    float bias = b3[e * D_H3 + n];
#pragma unroll
    for (int m = 0; m < 2; ++m)
#pragma unroll
      for (int j = 0; j < 4; ++j) {
        float v = acc3[m][j] + bias;
        v = v > 0.f ? v : 0.f;
        int rw = m * 16 + lg * 4 + j;
        *(f16*)(lds + H3_OFF + rw * 256 + ((n * 2) ^ ((rw & 15) << 4))) = (f16)v;
      }
  }
  __syncthreads();

  // ---------------- L4 + softmax (waves 0,1) ----------------
  if (wid < 2) {
    f32x4 a4 = (f32x4){0.f, 0.f, 0.f, 0.f};
#pragma unroll
    for (int kc = 0; kc < 4; ++kc) {
      f16x8 Bv = *(const f16x8*)(wpe4 + ln * 256 + kc * 64 + lg * 16);
      f16x8 Av = afrag(lds + H3_OFF, 256, wid * 16, kc * 64, lane);
      a4 = MFMA16(Av, Bv, a4);
    }
    float bias = b4[e * D_A + ln];
#pragma unroll
    for (int j = 0; j < 4; ++j) {
      float v = a4[j] + bias;
      float mx = v;
      for (int msk = 8; msk >= 1; msk >>= 1) mx = fmaxf(mx, __shfl_xor(mx, msk));
      float pe = expf(v - mx);
      float sm = pe;
      for (int msk = 8; msk >= 1; msk >>= 1) sm += __shfl_xor(sm, msk);
      int rl = wid * 16 + lg * 4 + j;
      if (rl < rvalid) out[(long)idx[row0 + rl] * D_A + ln] = pe / sm;
    }
  }
}

// ---------------- host ----------------

extern "C" void kernel_launch(void* const* d_in, const int* in_sizes, int n_in,
                              void* d_out, int out_size, void* d_ws, size_t ws_size,
                              hipStream_t stream) {
  const float* x  = (const float*)d_in[0];
  const int* pos  = (const int*)d_in[1];
  const float* W1 = (const float*)d_in[2];
  const float* b1 = (const float*)d_in[3];
  const float* W2 = (const float*)d_in[4];
  const float* b2 = (const float*)d_in[5];
  const float* W3 = (const float*)d_in[6];
  const float* b3 = (const float*)d_in[7];
  const float* W4 = (const float*)d_in[8];
  const float* b4 = (const float*)d_in[9];
  float* out = (float*)d_out;

  int* hdr = (int*)d_ws;
  int* idx = hdr + IDX_OFF;
  char* wp = (char*)d_ws + WP_OFF;

  hipLaunchKernelGGL(k_bucket, dim3(1), dim3(1024), 0, stream, pos, hdr, idx);
  hipLaunchKernelGGL(k_wcvt, dim3(WSLOTS / 256), dim3(256), 0, stream,
                     W1, W2, W3, W4, wp);
  hipLaunchKernelGGL(k_mlp, dim3(NTILE_MAX), dim3(THREADS), 0, stream,
                     x, b1, b2, b3, b4, hdr, idx, wp, out);
}

// Round 6
// 64.063 us; speedup vs baseline: 7.6836x; 1.2456x over previous
//
#include <hip/hip_runtime.h>

typedef _Float16 f16;
typedef __attribute__((ext_vector_type(8))) _Float16 f16x8;
typedef __attribute__((ext_vector_type(4))) _Float16 f16x4;
typedef __attribute__((ext_vector_type(4))) float f32x4;

#define MFMA16(a, b, c) __builtin_amdgcn_mfma_f32_16x16x32_f16(a, b, c, 0, 0, 0)

#define B_N 16384
#define E_N 9
#define TILE 32
#define NTILE_MAX 520  // = 8*65, XCD swizzle exact
#define THREADS 512

#define D_IN 512
#define D_H1 512
#define D_H2 256
#define D_H3 128
#define D_A 16

// Fragment-ordered fp16 weight image (byte offsets).
// 1KB records: lane l's 16B at rec*1024 + l*16. Lane (lg=l>>4, ln=l&15) holds
// row n(+ln), k-elems [k0+lg*8, +8) -- exactly the MFMA16 B-fragment.
// L1: per (e,wave): 64 frags f = g*4+kc*2+nf; n=w*64+(f>>5)*32+(f&1)*16+ln,
//     k=((f>>2)&7)*64+((f>>1)&1)*32+lg*8.
// L2: 32 frags; n=w*32+(f&1)*16+ln, k=(f>>2)*64+((f>>1)&1)*32+lg*8.
// L3: 8 frags;  n=w*16+ln,          k=(f>>1)*64+(f&1)*32+lg*8.
// L4: plain [16n][128k] per expert (4KB), direct per-lane loads.
#define O1B 0
#define O2B 4718592    // 9*8*64*1024
#define O3B 7077888    // +9*8*32*1024
#define O4B 7667712    // +9*8*8*1024
#define WPL_BYTES 7704576
#define WSLOTS (WPL_BYTES / 16)   // 481536 = 1881 * 256

#define IDX_OFF 64
#define WP_OFF 131584
#define WS_NEED (WP_OFF + (size_t)WPL_BYTES)

// LDS (bytes) -- 64KB total -> 2 blocks/CU
#define XS_OFF 0        // x fp16 [32][512] stride 1024, swz ((row&15)<<4)
#define H1_OFF 32768    // h1 fp16 [32][512] stride 1024
#define H2_OFF 0        // h2 [32][256] stride 512 (overlays x)
#define H3_OFF 16384    // h3 [32][128] stride 256 (overlays x)
#define LDS_BYTES 65536

// ---------------- bucketing ----------------

__global__ void k_bucket(const int* __restrict__ pos, int* __restrict__ hdr,
                         int* __restrict__ idx) {
  __shared__ int cnt[E_N], cur[E_N];
  __shared__ int flag_s;
  const int t = threadIdx.x;  // 1024
  if (t < E_N) cnt[t] = 0;
  if (t == 0) {
    int nz = 0;
    for (int i = 0; i < 64; ++i) nz |= pos[2 * i + 1];
    flag_s = (nz == 0) ? 1 : 0;  // int64 layout if all high words zero
  }
  __syncthreads();
  const bool f64 = flag_s != 0;
  int e[16];
#pragma unroll
  for (int k = 0; k < 16; ++k) {
    int i = k * 1024 + t;
    long long v = f64 ? ((const long long*)pos)[i] : (long long)pos[i];
    v = v < 0 ? 0 : (v > 8 ? 8 : v);
    e[k] = (int)v;
    atomicAdd(&cnt[e[k]], 1);
  }
  __syncthreads();
  if (t == 0) {
    int acc = 0;
    for (int ee = 0; ee < E_N; ++ee) { cur[ee] = acc; acc += cnt[ee]; }
  }
  if (t < E_N) hdr[8 + t] = cnt[t];
  __syncthreads();
#pragma unroll
  for (int k = 0; k < 16; ++k) {
    int i = k * 1024 + t;
    int slot = atomicAdd(&cur[e[k]], 1);
    idx[slot] = i;
  }
}

// ---------------- weight convert fp32 -> fragment-ordered fp16 image ----------------

__global__ void k_wcvt(const float* __restrict__ W1, const float* __restrict__ W2,
                       const float* __restrict__ W3, const float* __restrict__ W4,
                       char* __restrict__ wp) {
  int slot = blockIdx.x * 256 + threadIdx.x;
  if (slot >= WSLOTS) return;
  long addr = (long)slot << 4;
  int lane = (int)((addr >> 4) & 63);
  int lg = lane >> 4, ln = lane & 15;
  const float* src;
  if (addr < O2B) {
    int rec = (int)(addr >> 10);
    int f = rec & 63, w = (rec >> 6) & 7, e = rec >> 9;
    int n = w * 64 + (f >> 5) * 32 + (f & 1) * 16 + ln;
    int k = ((f >> 2) & 7) * 64 + ((f >> 1) & 1) * 32 + lg * 8;
    src = W1 + ((long)e * D_H1 + n) * D_IN + k;
  } else if (addr < O3B) {
    int rec = (int)((addr - O2B) >> 10);
    int f = rec & 31, w = (rec >> 5) & 7, e = rec >> 8;
    int n = w * 32 + (f & 1) * 16 + ln;
    int k = (f >> 2) * 64 + ((f >> 1) & 1) * 32 + lg * 8;
    src = W2 + ((long)e * D_H2 + n) * D_H1 + k;
  } else if (addr < O4B) {
    int rec = (int)((addr - O3B) >> 10);
    int f = rec & 7, w = (rec >> 3) & 7, e = rec >> 6;
    int n = w * 16 + ln;
    int k = (f >> 1) * 64 + (f & 1) * 32 + lg * 8;
    src = W3 + ((long)e * D_H3 + n) * D_H2 + k;
  } else {
    long rel = addr - O4B;
    int e = (int)(rel >> 12);
    int r2 = (int)(rel & 4095);
    int s = r2 >> 4, n = s >> 4, k16 = s & 15;
    src = W4 + ((long)e * D_A + n) * D_H3 + k16 * 8;
  }
  float4 a = *(const float4*)src;
  float4 b = *(const float4*)(src + 4);
  f16x8 h;
  h[0] = (f16)a.x; h[1] = (f16)a.y; h[2] = (f16)a.z; h[3] = (f16)a.w;
  h[4] = (f16)b.x; h[5] = (f16)b.y; h[6] = (f16)b.z; h[7] = (f16)b.w;
  *(f16x8*)(wp + addr) = h;
}

// ---------------- fused MLP ----------------

// A-fragment (16x16x32): lane m = rowoff + (l&15), k-bytes q + (l>>4)*16, XOR swz
__device__ __forceinline__ f16x8 afrag(const char* base, int strideB, int rowoff,
                                       int kbytes, int lane) {
  int m = rowoff + (lane & 15);
  int q = kbytes + ((lane >> 4) * 16);
  return *(const f16x8*)(base + m * strideB + (q ^ ((lane & 15) << 4)));
}

// load 4 / 2 consecutive 1KB B-fragment records (one dwordx4 per frag per lane)
__device__ __forceinline__ void ldfrag4(f16x8* q, const char* wb, int f0, int lane) {
  const char* p = wb + (long)f0 * 1024 + lane * 16;
  q[0] = *(const f16x8*)(p);
  q[1] = *(const f16x8*)(p + 1024);
  q[2] = *(const f16x8*)(p + 2048);
  q[3] = *(const f16x8*)(p + 3072);
}
__device__ __forceinline__ void ldfrag2(f16x8* q, const char* wb, int f0, int lane) {
  const char* p = wb + (long)f0 * 1024 + lane * 16;
  q[0] = *(const f16x8*)(p);
  q[1] = *(const f16x8*)(p + 1024);
}

__launch_bounds__(THREADS, 4)  // 4 waves/EU -> 2 blocks/CU (64KB LDS each)
__global__ void k_mlp(const float* __restrict__ x,
                      const float* __restrict__ b1, const float* __restrict__ b2,
                      const float* __restrict__ b3, const float* __restrict__ b4,
                      const int* __restrict__ hdr, const int* __restrict__ idx,
                      const char* __restrict__ wp, float* __restrict__ out) {
  __shared__ __align__(16) char lds[LDS_BYTES];

  int b = blockIdx.x;
  int bswz = (b & 7) * (NTILE_MAX / 8) + (b >> 3);  // bijective, 520 = 8*65

  const int* counts = hdr + 8;
  int e = -1, tile = 0, base = 0, ne = 0;
  {
    int acc = 0, off = 0;
    for (int ee = 0; ee < E_N; ++ee) {
      int n = counts[ee];
      int nt = (n + TILE - 1) / TILE;
      if (bswz < acc + nt) { e = ee; tile = bswz - acc; ne = n; base = off; break; }
      acc += nt; off += n;
    }
  }
  if (e < 0) return;
  const int rvalid = min(TILE, ne - tile * TILE);
  const int row0 = base + tile * TILE;

  const int t = threadIdx.x;
  const int lane = t & 63;
  const int wid = t >> 6;
  const int lg = lane >> 4;
  const int ln = lane & 15;

  const char* wb1 = wp + O1B + (((long)e * 8 + wid) << 16);
  const char* wb2 = wp + O2B + (((long)e * 8 + wid) << 15);
  const char* wb3 = wp + O3B + (((long)e * 8 + wid) << 13);
  const char* wpe4 = wp + O4B + (long)e * 4096;

  f16x8 Q[3][4];
  // L1 prologue: issue before x staging (hidden under the staging + barrier)
  ldfrag4(Q[0], wb1, 0, lane);
  ldfrag4(Q[1], wb1, 4, lane);

  // ---- stage x tile as fp16, XOR-swizzled ----
  const float4* x4 = (const float4*)x;
  for (int u = t; u < TILE * (D_IN / 4); u += THREADS) {
    int s = u >> 7, c4 = u & 127;
    float4 v = make_float4(0.f, 0.f, 0.f, 0.f);
    if (s < rvalid) v = x4[(long)idx[row0 + s] * (D_IN / 4) + c4];
    f16x4 h;
    h[0] = (f16)v.x; h[1] = (f16)v.y; h[2] = (f16)v.z; h[3] = (f16)v.w;
    *(f16x4*)(lds + XS_OFF + s * 1024 + ((c4 * 8) ^ ((s & 15) << 4))) = h;
  }
  __syncthreads();

  // ---------------- L1: h1[32x512] = x @ W1^T ----------------
  {
    f32x4 acc[2][2];
#pragma unroll
    for (int g = 0; g < 16; ++g) {
      if (g < 14) ldfrag4(Q[(g + 2) % 3], wb1, (g + 2) * 4, lane);
      const int kb = g & 7;
      if (kb == 0) {
#pragma unroll
        for (int m = 0; m < 2; ++m)
#pragma unroll
          for (int nf = 0; nf < 2; ++nf) acc[m][nf] = (f32x4){0.f, 0.f, 0.f, 0.f};
      }
      f16x8* cq = Q[g % 3];
      __builtin_amdgcn_s_setprio(1);
#pragma unroll
      for (int kc = 0; kc < 2; ++kc) {
        f16x8 A0 = afrag(lds + XS_OFF, 1024, 0, kb * 128 + kc * 64, lane);
        f16x8 A1 = afrag(lds + XS_OFF, 1024, 16, kb * 128 + kc * 64, lane);
        acc[0][0] = MFMA16(A0, cq[kc * 2 + 0], acc[0][0]);
        acc[0][1] = MFMA16(A0, cq[kc * 2 + 1], acc[0][1]);
        acc[1][0] = MFMA16(A1, cq[kc * 2 + 0], acc[1][0]);
        acc[1][1] = MFMA16(A1, cq[kc * 2 + 1], acc[1][1]);
      }
      __builtin_amdgcn_s_setprio(0);
      if (kb == 7) {
        const int nf32 = g >> 3;
#pragma unroll
        for (int nf = 0; nf < 2; ++nf) {
          int n = wid * 64 + nf32 * 32 + nf * 16 + ln;
          float bias = b1[e * D_H1 + n];
#pragma unroll
          for (int m = 0; m < 2; ++m)
#pragma unroll
            for (int j = 0; j < 4; ++j) {
              float v = acc[m][nf][j] + bias;
              v = v > 0.f ? v : 0.f;
              int rw = m * 16 + lg * 4 + j;
              *(f16*)(lds + H1_OFF + rw * 1024 + ((n * 2) ^ ((rw & 15) << 4))) = (f16)v;
            }
        }
      }
    }
  }
  __syncthreads();

  // ---------------- L2: h2[32x256] = h1 @ W2^T ----------------
  {
    ldfrag4(Q[0], wb2, 0, lane);
    ldfrag4(Q[1], wb2, 4, lane);
    f32x4 acc[2][2];
#pragma unroll
    for (int m = 0; m < 2; ++m)
#pragma unroll
      for (int nf = 0; nf < 2; ++nf) acc[m][nf] = (f32x4){0.f, 0.f, 0.f, 0.f};
#pragma unroll
    for (int g = 0; g < 8; ++g) {
      if (g < 6) ldfrag4(Q[(g + 2) % 3], wb2, (g + 2) * 4, lane);
      f16x8* cq = Q[g % 3];
      __builtin_amdgcn_s_setprio(1);
#pragma unroll
      for (int kc = 0; kc < 2; ++kc) {
        f16x8 A0 = afrag(lds + H1_OFF, 1024, 0, g * 128 + kc * 64, lane);
        f16x8 A1 = afrag(lds + H1_OFF, 1024, 16, g * 128 + kc * 64, lane);
        acc[0][0] = MFMA16(A0, cq[kc * 2 + 0], acc[0][0]);
        acc[0][1] = MFMA16(A0, cq[kc * 2 + 1], acc[0][1]);
        acc[1][0] = MFMA16(A1, cq[kc * 2 + 0], acc[1][0]);
        acc[1][1] = MFMA16(A1, cq[kc * 2 + 1], acc[1][1]);
      }
      __builtin_amdgcn_s_setprio(0);
    }
#pragma unroll
    for (int nf = 0; nf < 2; ++nf) {
      int n = wid * 32 + nf * 16 + ln;
      float bias = b2[e * D_H2 + n];
#pragma unroll
      for (int m = 0; m < 2; ++m)
#pragma unroll
        for (int j = 0; j < 4; ++j) {
          float v = acc[m][nf][j] + bias;
          v = v > 0.f ? v : 0.f;
          int rw = m * 16 + lg * 4 + j;
          *(f16*)(lds + H2_OFF + rw * 512 + ((n * 2) ^ ((rw & 15) << 4))) = (f16)v;
        }
    }
  }
  __syncthreads();

  // ---------------- L3: h3[32x128] = h2 @ W3^T ----------------
  {
    ldfrag2(Q[0], wb3, 0, lane);
    ldfrag2(Q[1], wb3, 2, lane);
    f32x4 acc3[2];
    acc3[0] = (f32x4){0.f, 0.f, 0.f, 0.f};
    acc3[1] = (f32x4){0.f, 0.f, 0.f, 0.f};
#pragma unroll
    for (int g = 0; g < 4; ++g) {
      if (g < 2) ldfrag2(Q[(g + 2) % 3], wb3, (g + 2) * 2, lane);
      f16x8* cq = Q[g % 3];
      __builtin_amdgcn_s_setprio(1);
#pragma unroll
      for (int kc = 0; kc < 2; ++kc) {
        f16x8 B0 = cq[kc];
#pragma unroll
        for (int m = 0; m < 2; ++m) {
          f16x8 A = afrag(lds + H2_OFF, 512, m * 16, g * 128 + kc * 64, lane);
          acc3[m] = MFMA16(A, B0, acc3[m]);
        }
      }
      __builtin_amdgcn_s_setprio(0);
    }
    int n = wid * 16 + ln;
    float bias = b3[e * D_H3 + n];
#pragma unroll
    for (int m = 0; m < 2; ++m)
#pragma unroll
      for (int j = 0; j < 4; ++j) {
        float v = acc3[m][j] + bias;
        v = v > 0.f ? v : 0.f;
        int rw = m * 16 + lg * 4 + j;
        *(f16*)(lds + H3_OFF + rw * 256 + ((n * 2) ^ ((rw & 15) << 4))) = (f16)v;
      }
  }
  __syncthreads();

  // ---------------- L4 + softmax (waves 0,1) ----------------
  if (wid < 2) {
    f32x4 a4 = (f32x4){0.f, 0.f, 0.f, 0.f};
#pragma unroll
    for (int kc = 0; kc < 4; ++kc) {
      f16x8 Bv = *(const f16x8*)(wpe4 + ln * 256 + kc * 64 + lg * 16);
      f16x8 Av = afrag(lds + H3_OFF, 256, wid * 16, kc * 64, lane);
      a4 = MFMA16(Av, Bv, a4);
    }
    float bias = b4[e * D_A + ln];
#pragma unroll
    for (int j = 0; j < 4; ++j) {
      float v = a4[j] + bias;
      float mx = v;
      for (int msk = 8; msk >= 1; msk >>= 1) mx = fmaxf(mx, __shfl_xor(mx, msk));
      float pe = expf(v - mx);
      float sm = pe;
      for (int msk = 8; msk >= 1; msk >>= 1) sm += __shfl_xor(sm, msk);
      int rl = wid * 16 + lg * 4 + j;
      if (rl < rvalid) out[(long)idx[row0 + rl] * D_A + ln] = pe / sm;
    }
  }
}

// ---------------- host ----------------

extern "C" void kernel_launch(void* const* d_in, const int* in_sizes, int n_in,
                              void* d_out, int out_size, void* d_ws, size_t ws_size,
                              hipStream_t stream) {
  const float* x  = (const float*)d_in[0];
  const int* pos  = (const int*)d_in[1];
  const float* W1 = (const float*)d_in[2];
  const float* b1 = (const float*)d_in[3];
  const float* W2 = (const float*)d_in[4];
  const float* b2 = (const float*)d_in[5];
  const float* W3 = (const float*)d_in[6];
  const float* b3 = (const float*)d_in[7];
  const float* W4 = (const float*)d_in[8];
  const float* b4 = (const float*)d_in[9];
  float* out = (float*)d_out;

  int* hdr = (int*)d_ws;
  int* idx = hdr + IDX_OFF;
  char* wp = (char*)d_ws + WP_OFF;

  hipLaunchKernelGGL(k_bucket, dim3(1), dim3(1024), 0, stream, pos, hdr, idx);
  hipLaunchKernelGGL(k_wcvt, dim3(WSLOTS / 256), dim3(256), 0, stream,
                     W1, W2, W3, W4, wp);
  hipLaunchKernelGGL(k_mlp, dim3(NTILE_MAX), dim3(THREADS), 0, stream,
                     x, b1, b2, b3, b4, hdr, idx, wp, out);
}